// Round 2
// baseline (197.618 us; speedup 1.0000x reference)
//
#include <hip/hip_runtime.h>
#include <stdint.h>

typedef float f32x4 __attribute__((ext_vector_type(4)));
typedef short bf16x8 __attribute__((ext_vector_type(8)));
typedef uint32_t u32;

// d_ws layout (u32 units): fragment-ordered bf16 weights
#define W1_OFF 0u       // 16 kt * 4 nt  frags, 256 u32 each
#define W2_OFF 16384u   //  2 kt * 4 nt
#define W3_OFF 18432u   //  2 kt * 32 nt
#define W4_OFF 34816u   // 16 kt * 32 nt
#define WS_BYTES (165888u * 4u)

__device__ __forceinline__ u32 f2bf(float f) {
  u32 b = __builtin_bit_cast(u32, f);
  return (b + 0x7FFFu + ((b >> 16) & 1u)) >> 16;  // RNE bf16
}
__device__ __forceinline__ u32 pack2(float lo, float hi) {
  return f2bf(lo) | (f2bf(hi) << 16);
}
__device__ __forceinline__ bf16x8 ld_frag(const u32* p) {
  union { uint4 u; bf16x8 v; } t;
  t.u = *reinterpret_cast<const uint4*>(p);
  return t.v;
}
__device__ __forceinline__ f32x4 mfma16(bf16x8 a, bf16x8 b, f32x4 c) {
  return __builtin_amdgcn_mfma_f32_16x16x32_bf16(a, b, c, 0, 0, 0);
}

// ---------------- prep: repack weights into fragment-ordered bf16 ----------------
// frag element j of lane l holds W[kt*32 + 4*(l>>4) + (j&3) + 16*(j>>2)][nt*16 + (l&15)]
__global__ void prep_kernel(const float* __restrict__ W1, const float* __restrict__ W2,
                            const float* __restrict__ W3, const float* __restrict__ W4,
                            u32* __restrict__ ws) {
  int t = blockIdx.x * 256 + threadIdx.x;
  if (t >= 648 * 64) return;
  int f = t >> 6, l = t & 63;
  const float* W; int N, NT, fi; u32 off;
  if (f < 64)       { W = W1; N = 64;  NT = 4;  fi = f;       off = W1_OFF; }
  else if (f < 72)  { W = W2; N = 64;  NT = 4;  fi = f - 64;  off = W2_OFF; }
  else if (f < 136) { W = W3; N = 512; NT = 32; fi = f - 72;  off = W3_OFF; }
  else              { W = W4; N = 512; NT = 32; fi = f - 136; off = W4_OFF; }
  int kt = fi / NT, nt = fi % NT;
  int g = l >> 4, i = l & 15;
  int n = nt * 16 + i;
  int kb = kt * 32 + 4 * g;
  u32 w0 = pack2(W[(size_t)(kb + 0) * N + n],  W[(size_t)(kb + 1) * N + n]);
  u32 w1 = pack2(W[(size_t)(kb + 2) * N + n],  W[(size_t)(kb + 3) * N + n]);
  u32 w2 = pack2(W[(size_t)(kb + 16) * N + n], W[(size_t)(kb + 17) * N + n]);
  u32 w3 = pack2(W[(size_t)(kb + 18) * N + n], W[(size_t)(kb + 19) * N + n]);
  *reinterpret_cast<uint4*>(ws + off + (u32)fi * 256u + (u32)l * 4u) = make_uint4(w0, w1, w2, w3);
}

// ---------------- fused main kernel (LDS-free, swapped-operand chaining) ----------------
// 512 blocks x 256 threads; each wave owns 16 rows end-to-end, all state in registers.
// Swapped GEMMs (mfma(Wfrag, actfrag)) yield D^T with lane&15 = m and the n-dim laid out
// as 16*nt + 4*g + r — which is exactly the B-operand k-slice layout for the next GEMM.
__global__ __launch_bounds__(256, 3) void fused_kernel(
    const float* __restrict__ x, const float* __restrict__ noise,
    const u32* __restrict__ ws,
    const float* __restrict__ b1, const float* __restrict__ b2,
    const float* __restrict__ b3, const float* __restrict__ b4,
    const float* __restrict__ omega, const float* __restrict__ Kp,
    const float* __restrict__ alphap, float* __restrict__ out) {
  const int tid = threadIdx.x;
  const int l = tid & 63;
  const int g = l >> 4, i = l & 15;
  const int m0 = blockIdx.x * 64 + (tid >> 6) * 16;  // global row base for this wave

  // ---- GEMM1 (swapped): D1T[n1][m] = sum_k W1[k][n1] * x[m][k]
  f32x4 acc1T[4] = {};
  {
    const float* xr = x + (size_t)(m0 + i) * 512 + 4 * g;
#pragma unroll
    for (int kt = 0; kt < 16; ++kt) {
      const float4 a0 = *reinterpret_cast<const float4*>(xr + kt * 32);
      const float4 a1 = *reinterpret_cast<const float4*>(xr + kt * 32 + 16);
      union { u32 u[4]; bf16x8 v; } xf;
      xf.u[0] = pack2(a0.x, a0.y); xf.u[1] = pack2(a0.z, a0.w);
      xf.u[2] = pack2(a1.x, a1.y); xf.u[3] = pack2(a1.z, a1.w);
#pragma unroll
      for (int nt = 0; nt < 4; ++nt)
        acc1T[nt] = mfma16(ld_frag(ws + W1_OFF + (u32)(kt * 4 + nt) * 256u + (u32)l * 4u),
                           xf.v, acc1T[nt]);
    }
  }
  // tanh + b1, pack D1T tiles (2kt2, 2kt2+1) into GEMM2 B-frags
  bf16x8 hfrag[2];
#pragma unroll
  for (int kt2 = 0; kt2 < 2; ++kt2) {
    union { u32 u[4]; bf16x8 v; } t;
#pragma unroll
    for (int q = 0; q < 2; ++q) {
      int nt = 2 * kt2 + q;
      int nb = 16 * nt + 4 * g;
      float v0 = tanhf(acc1T[nt][0] + b1[nb + 0]);
      float v1 = tanhf(acc1T[nt][1] + b1[nb + 1]);
      float v2 = tanhf(acc1T[nt][2] + b1[nb + 2]);
      float v3 = tanhf(acc1T[nt][3] + b1[nb + 3]);
      t.u[2 * q + 0] = pack2(v0, v1);
      t.u[2 * q + 1] = pack2(v2, v3);
    }
    hfrag[kt2] = t.v;
  }

  // ---- GEMM2 (swapped): phases^T: lane&15 = m, o = 16*ot + 4*g + r
  f32x4 acc2T[4] = {};
#pragma unroll
  for (int kt2 = 0; kt2 < 2; ++kt2)
#pragma unroll
    for (int ot = 0; ot < 4; ++ot)
      acc2T[ot] = mfma16(ld_frag(ws + W2_OFF + (u32)(kt2 * 4 + ot) * 256u + (u32)l * 4u),
                         hfrag[kt2], acc2T[ot]);

  // ---- Kuramoto (in-register; mean over 64 osc = 16 local + 2-shuffle reduce)
  float ph[4][4], om[4][4];
  const float Kc = Kp[0];
#pragma unroll
  for (int ot = 0; ot < 4; ++ot) {
    int ob = 16 * ot + 4 * g;
#pragma unroll
    for (int r = 0; r < 4; ++r) {
      ph[ot][r] = acc2T[ot][r] + b2[ob + r];
      om[ot][r] = omega[ob + r];
    }
  }
#pragma unroll
  for (int s = 0; s < 10; ++s) {
    float rs = 0.f;
    float cs[4][4];
#pragma unroll
    for (int ot = 0; ot < 4; ++ot)
#pragma unroll
      for (int r = 0; r < 4; ++r) {
        rs += __sinf(ph[ot][r]);
        cs[ot][r] = __cosf(ph[ot][r]);
      }
    rs += __shfl_xor(rs, 16);
    rs += __shfl_xor(rs, 32);
    float sc = 0.01f * Kc * rs * 0.015625f;  // DT * K * mean_field
#pragma unroll
    for (int ot = 0; ot < 4; ++ot)
#pragma unroll
      for (int r = 0; r < 4; ++r)
        ph[ot][r] += 0.01f * om[ot][r] + sc * cs[ot][r];
  }
  // pack phases into GEMM3 B-frags (same tile-pair pattern, no bias)
  bf16x8 pfrag[2];
#pragma unroll
  for (int kt2 = 0; kt2 < 2; ++kt2) {
    union { u32 u[4]; bf16x8 v; } t;
#pragma unroll
    for (int q = 0; q < 2; ++q) {
      int nt = 2 * kt2 + q;
      t.u[2 * q + 0] = pack2(ph[nt][0], ph[nt][1]);
      t.u[2 * q + 1] = pack2(ph[nt][2], ph[nt][3]);
    }
    pfrag[kt2] = t.v;
  }

  // ---- GEMM3 (swapped, chunked): builds GEMM4 A-frags afr[16] directly in registers
  bf16x8 afr[16];
#pragma unroll
  for (int c = 0; c < 4; ++c) {
    f32x4 a3[8] = {};
#pragma unroll
    for (int kt = 0; kt < 2; ++kt)
#pragma unroll
      for (int nt = 0; nt < 8; ++nt)
        a3[nt] = mfma16(ld_frag(ws + W3_OFF + (u32)(kt * 32 + c * 8 + nt) * 256u + (u32)l * 4u),
                        pfrag[kt], a3[nt]);
#pragma unroll
    for (int q = 0; q < 4; ++q) {
      union { u32 u[4]; bf16x8 v; } t;
#pragma unroll
      for (int p = 0; p < 2; ++p) {
        int nt = 2 * q + p;
        int nb = 16 * (8 * c + nt) + 4 * g;
        float v0 = a3[nt][0] + b3[nb + 0]; v0 = v0 > 0.f ? v0 : 0.f;
        float v1 = a3[nt][1] + b3[nb + 1]; v1 = v1 > 0.f ? v1 : 0.f;
        float v2 = a3[nt][2] + b3[nb + 2]; v2 = v2 > 0.f ? v2 : 0.f;
        float v3 = a3[nt][3] + b3[nb + 3]; v3 = v3 > 0.f ? v3 : 0.f;
        t.u[2 * p + 0] = pack2(v0, v1);
        t.u[2 * p + 1] = pack2(v2, v3);
      }
      afr[4 * c + q] = t.v;
    }
  }

  // ---- GEMM4 (normal) + fused quaternion epilogue, 8 chunks of 64 cols
  const float alpha = alphap[0];
  for (int c4 = 0; c4 < 8; ++c4) {
    // prefetch noise for this chunk (hidden under the 64 MFMAs below)
    float nz[16];
#pragma unroll
    for (int nt = 0; nt < 4; ++nt)
#pragma unroll
      for (int r = 0; r < 4; ++r)
        nz[nt * 4 + r] = noise[(size_t)(m0 + 4 * g + r) * 512 + c4 * 64 + nt * 16 + i];
    f32x4 acc[4] = {};
#pragma unroll
    for (int kt = 0; kt < 16; ++kt)
#pragma unroll
      for (int nt = 0; nt < 4; ++nt)
        acc[nt] = mfma16(afr[kt],
                         ld_frag(ws + W4_OFF + (u32)(kt * 32 + c4 * 4 + nt) * 256u + (u32)l * 4u),
                         acc[nt]);
#pragma unroll
    for (int nt = 0; nt < 4; ++nt) {
      int col = c4 * 64 + nt * 16 + i;
      float bb = b4[col];
      float fmv = __sinf(alpha * (float)col);
#pragma unroll
      for (int r = 0; r < 4; ++r) {
        size_t idx = (size_t)(m0 + 4 * g + r) * 512 + col;
        float im = nz[nt * 4 + r] * fmv;
        float4 o = make_float4(acc[nt][r] + bb, im, im, im);
        *reinterpret_cast<float4*>(out + idx * 4) = o;
      }
    }
  }
}

extern "C" void kernel_launch(void* const* d_in, const int* in_sizes, int n_in,
                              void* d_out, int out_size, void* d_ws, size_t ws_size,
                              hipStream_t stream) {
  if (ws_size < WS_BYTES) return;  // need 648 KB fragment-ordered weights
  const float* x      = (const float*)d_in[0];
  const float* noise  = (const float*)d_in[1];
  const float* W1     = (const float*)d_in[2];
  const float* b1     = (const float*)d_in[3];
  const float* W2     = (const float*)d_in[4];
  const float* b2     = (const float*)d_in[5];
  const float* W3     = (const float*)d_in[6];
  const float* b3     = (const float*)d_in[7];
  const float* W4     = (const float*)d_in[8];
  const float* b4     = (const float*)d_in[9];
  const float* omega  = (const float*)d_in[10];
  const float* Kp     = (const float*)d_in[11];
  const float* alphap = (const float*)d_in[12];
  u32* ws = (u32*)d_ws;
  prep_kernel<<<162, 256, 0, stream>>>(W1, W2, W3, W4, ws);
  fused_kernel<<<512, 256, 0, stream>>>(x, noise, ws, b1, b2, b3, b4,
                                        omega, Kp, alphap, (float*)d_out);
}

// Round 3
// 136.762 us; speedup vs baseline: 1.4450x; 1.4450x over previous
//
#include <hip/hip_runtime.h>
#include <stdint.h>

typedef float f32x4 __attribute__((ext_vector_type(4)));
typedef short bf16x8 __attribute__((ext_vector_type(8)));
typedef uint32_t u32;

// d_ws layout (u32 units): fragment-ordered bf16 weights, then f-fragments
#define W1_OFF 0u       // 16 kt * 4 nt  frags, 256 u32 each
#define W2_OFF 16384u   //  2 kt * 4 nt
#define W3_OFF 18432u   //  2 kt * 32 nt
#define W4_OFF 34816u   // 16 kt * 32 nt
#define F_OFF  165888u  // 2048 rowgroups * 16 kt * 64 lanes * 4 u32 = 32 MB
#define WS_WEIGHTS_BYTES (165888u * 4u)
#define WS_NEED_BYTES ((165888ull + 2048ull * 16u * 64u * 4u) * 4ull)

__device__ __forceinline__ u32 f2bf(float f) {
  u32 b = __builtin_bit_cast(u32, f);
  return (b + 0x7FFFu + ((b >> 16) & 1u)) >> 16;  // RNE bf16
}
__device__ __forceinline__ u32 pack2(float lo, float hi) {
  return f2bf(lo) | (f2bf(hi) << 16);
}
__device__ __forceinline__ bf16x8 ld_frag(const u32* p) {
  union { uint4 u; bf16x8 v; } t;
  t.u = *reinterpret_cast<const uint4*>(p);
  return t.v;
}
__device__ __forceinline__ f32x4 mfma16(bf16x8 a, bf16x8 b, f32x4 c) {
  return __builtin_amdgcn_mfma_f32_16x16x32_bf16(a, b, c, 0, 0, 0);
}

// ---------------- prep: repack weights into fragment-ordered bf16 ----------------
// frag element j of lane l holds W[kt*32 + 4*(l>>4) + (j&3) + 16*(j>>2)][nt*16 + (l&15)]
__global__ void prep_kernel(const float* __restrict__ W1, const float* __restrict__ W2,
                            const float* __restrict__ W3, const float* __restrict__ W4,
                            u32* __restrict__ ws) {
  int t = blockIdx.x * 256 + threadIdx.x;
  if (t >= 648 * 64) return;
  int f = t >> 6, l = t & 63;
  const float* W; int N, NT, fi; u32 off;
  if (f < 64)       { W = W1; N = 64;  NT = 4;  fi = f;       off = W1_OFF; }
  else if (f < 72)  { W = W2; N = 64;  NT = 4;  fi = f - 64;  off = W2_OFF; }
  else if (f < 136) { W = W3; N = 512; NT = 32; fi = f - 72;  off = W3_OFF; }
  else              { W = W4; N = 512; NT = 32; fi = f - 136; off = W4_OFF; }
  int kt = fi / NT, nt = fi % NT;
  int g = l >> 4, i = l & 15;
  int n = nt * 16 + i;
  int kb = kt * 32 + 4 * g;
  u32 w0 = pack2(W[(size_t)(kb + 0) * N + n],  W[(size_t)(kb + 1) * N + n]);
  u32 w1 = pack2(W[(size_t)(kb + 2) * N + n],  W[(size_t)(kb + 3) * N + n]);
  u32 w2 = pack2(W[(size_t)(kb + 16) * N + n], W[(size_t)(kb + 17) * N + n]);
  u32 w3 = pack2(W[(size_t)(kb + 18) * N + n], W[(size_t)(kb + 19) * N + n]);
  *reinterpret_cast<uint4*>(ws + off + (u32)fi * 256u + (u32)l * 4u) = make_uint4(w0, w1, w2, w3);
}

// ---------------- kernel A: GEMM1+tanh+GEMM2+Kuramoto+GEMM3+relu -> f-frags ----------------
// Swapped-operand chaining (verified R2): each GEMM computed transposed so its output is
// already the next GEMM's B-operand fragment. Stores GEMM4 A-frags to ws.
__global__ __launch_bounds__(256, 2) void front_kernel(
    const float* __restrict__ x, const u32* __restrict__ wsr, u32* __restrict__ wsw,
    const float* __restrict__ b1, const float* __restrict__ b2,
    const float* __restrict__ b3, const float* __restrict__ omega,
    const float* __restrict__ Kp) {
  const int tid = threadIdx.x;
  const int l = tid & 63;
  const int g = l >> 4, i = l & 15;
  const int rowgrp = blockIdx.x * 4 + (tid >> 6);
  const int m0 = rowgrp * 16;

  // ---- GEMM1 (swapped): D1T[n1][m] = sum_k W1[k][n1] * x[m][k]
  f32x4 acc1T[4] = {};
  {
    const float* xr = x + (size_t)(m0 + i) * 512 + 4 * g;
#pragma unroll
    for (int kt = 0; kt < 16; ++kt) {
      const float4 a0 = *reinterpret_cast<const float4*>(xr + kt * 32);
      const float4 a1 = *reinterpret_cast<const float4*>(xr + kt * 32 + 16);
      union { u32 u[4]; bf16x8 v; } xf;
      xf.u[0] = pack2(a0.x, a0.y); xf.u[1] = pack2(a0.z, a0.w);
      xf.u[2] = pack2(a1.x, a1.y); xf.u[3] = pack2(a1.z, a1.w);
#pragma unroll
      for (int nt = 0; nt < 4; ++nt)
        acc1T[nt] = mfma16(ld_frag(wsr + W1_OFF + (u32)(kt * 4 + nt) * 256u + (u32)l * 4u),
                           xf.v, acc1T[nt]);
    }
  }
  // tanh + b1 -> GEMM2 B-frags
  bf16x8 hfrag[2];
#pragma unroll
  for (int kt2 = 0; kt2 < 2; ++kt2) {
    union { u32 u[4]; bf16x8 v; } t;
#pragma unroll
    for (int q = 0; q < 2; ++q) {
      int nt = 2 * kt2 + q;
      int nb = 16 * nt + 4 * g;
      float v0 = tanhf(acc1T[nt][0] + b1[nb + 0]);
      float v1 = tanhf(acc1T[nt][1] + b1[nb + 1]);
      float v2 = tanhf(acc1T[nt][2] + b1[nb + 2]);
      float v3 = tanhf(acc1T[nt][3] + b1[nb + 3]);
      t.u[2 * q + 0] = pack2(v0, v1);
      t.u[2 * q + 1] = pack2(v2, v3);
    }
    hfrag[kt2] = t.v;
  }

  // ---- GEMM2 (swapped)
  f32x4 acc2T[4] = {};
#pragma unroll
  for (int kt2 = 0; kt2 < 2; ++kt2)
#pragma unroll
    for (int ot = 0; ot < 4; ++ot)
      acc2T[ot] = mfma16(ld_frag(wsr + W2_OFF + (u32)(kt2 * 4 + ot) * 256u + (u32)l * 4u),
                         hfrag[kt2], acc2T[ot]);

  // ---- Kuramoto (in-register)
  float ph[4][4], om[4][4];
  const float Kc = Kp[0];
#pragma unroll
  for (int ot = 0; ot < 4; ++ot) {
    int ob = 16 * ot + 4 * g;
#pragma unroll
    for (int r = 0; r < 4; ++r) {
      ph[ot][r] = acc2T[ot][r] + b2[ob + r];
      om[ot][r] = omega[ob + r];
    }
  }
#pragma unroll
  for (int s = 0; s < 10; ++s) {
    float rs = 0.f;
    float cs[4][4];
#pragma unroll
    for (int ot = 0; ot < 4; ++ot)
#pragma unroll
      for (int r = 0; r < 4; ++r) {
        rs += __sinf(ph[ot][r]);
        cs[ot][r] = __cosf(ph[ot][r]);
      }
    rs += __shfl_xor(rs, 16);
    rs += __shfl_xor(rs, 32);
    float sc = 0.01f * Kc * rs * 0.015625f;
#pragma unroll
    for (int ot = 0; ot < 4; ++ot)
#pragma unroll
      for (int r = 0; r < 4; ++r)
        ph[ot][r] += 0.01f * om[ot][r] + sc * cs[ot][r];
  }
  bf16x8 pfrag[2];
#pragma unroll
  for (int kt2 = 0; kt2 < 2; ++kt2) {
    union { u32 u[4]; bf16x8 v; } t;
#pragma unroll
    for (int q = 0; q < 2; ++q) {
      int nt = 2 * kt2 + q;
      t.u[2 * q + 0] = pack2(ph[nt][0], ph[nt][1]);
      t.u[2 * q + 1] = pack2(ph[nt][2], ph[nt][3]);
    }
    pfrag[kt2] = t.v;
  }

  // ---- GEMM3 (swapped, chunked) -> store GEMM4 A-frags to ws (streamed, low pressure)
#pragma unroll
  for (int c = 0; c < 4; ++c) {
    f32x4 a3[8] = {};
#pragma unroll
    for (int kt = 0; kt < 2; ++kt)
#pragma unroll
      for (int nt = 0; nt < 8; ++nt)
        a3[nt] = mfma16(ld_frag(wsr + W3_OFF + (u32)(kt * 32 + c * 8 + nt) * 256u + (u32)l * 4u),
                        pfrag[kt], a3[nt]);
#pragma unroll
    for (int q = 0; q < 4; ++q) {
      union { uint4 u4; u32 u[4]; } t;
#pragma unroll
      for (int p = 0; p < 2; ++p) {
        int nt = 2 * q + p;
        int nb = 16 * (8 * c + nt) + 4 * g;
        float v0 = a3[nt][0] + b3[nb + 0]; v0 = v0 > 0.f ? v0 : 0.f;
        float v1 = a3[nt][1] + b3[nb + 1]; v1 = v1 > 0.f ? v1 : 0.f;
        float v2 = a3[nt][2] + b3[nb + 2]; v2 = v2 > 0.f ? v2 : 0.f;
        float v3 = a3[nt][3] + b3[nb + 3]; v3 = v3 > 0.f ? v3 : 0.f;
        t.u[2 * p + 0] = pack2(v0, v1);
        t.u[2 * p + 1] = pack2(v2, v3);
      }
      int kt4 = 4 * c + q;
      *reinterpret_cast<uint4*>(wsw + F_OFF +
          ((u32)(rowgrp * 16 + kt4) * 64u + (u32)l) * 4u) = t.u4;
    }
  }
}

// ---------------- kernel B: GEMM4 + quaternion epilogue ----------------
// 2048 blocks x 512 threads (8 waves); block owns 16 rows x 512 cols; wave owns 16x64.
// A-frags staged once into LDS; B-frags streamed from L2-hot fragment-ordered W4.
__global__ __launch_bounds__(512, 2) void gemm4_kernel(
    const float* __restrict__ noise, const u32* __restrict__ ws,
    const float* __restrict__ b4, const float* __restrict__ alphap,
    float* __restrict__ out) {
  __shared__ uint4 fst[1024];  // 16 KB: this block's 16 A-frags
  const int tid = threadIdx.x;
  const int wave = tid >> 6, l = tid & 63;
  const int g = l >> 4, i = l & 15;
  const int rowgrp = blockIdx.x;
  const int m0 = rowgrp * 16;
  const int c0 = wave * 64;

  // stage A-frags: straight 16 KB copy
  {
    const uint4* src = reinterpret_cast<const uint4*>(ws + F_OFF + (u32)rowgrp * 16384u / 4u * 1u);
    // F block for rowgrp: 16 kt * 64 lanes * 16 B = 16384 B = 1024 uint4
    fst[tid] = src[tid];
    fst[tid + 512] = src[tid + 512];
  }
  // prefetch noise + per-col constants while staging lands
  const float alpha = alphap[0];
  float nz[16], fmv[4], bb[4];
#pragma unroll
  for (int nt = 0; nt < 4; ++nt) {
    int col = c0 + nt * 16 + i;
    fmv[nt] = __sinf(alpha * (float)col);
    bb[nt] = b4[col];
#pragma unroll
    for (int r = 0; r < 4; ++r)
      nz[nt * 4 + r] = noise[(size_t)(m0 + 4 * g + r) * 512 + col];
  }
  __syncthreads();

  // K-loop: 16 kt, 4 MFMA each
  f32x4 acc[4] = {};
#pragma unroll
  for (int kt = 0; kt < 16; ++kt) {
    union { uint4 u; bf16x8 v; } a;
    a.u = fst[kt * 64 + l];
#pragma unroll
    for (int nt = 0; nt < 4; ++nt)
      acc[nt] = mfma16(a.v,
                       ld_frag(ws + W4_OFF + (u32)(kt * 32 + wave * 4 + nt) * 256u + (u32)l * 4u),
                       acc[nt]);
  }

  // epilogue: quaternion assembly, coalesced float4 stores
#pragma unroll
  for (int nt = 0; nt < 4; ++nt) {
    int col = c0 + nt * 16 + i;
#pragma unroll
    for (int r = 0; r < 4; ++r) {
      size_t idx = (size_t)(m0 + 4 * g + r) * 512 + col;
      float im = nz[nt * 4 + r] * fmv[nt];
      float4 o = make_float4(acc[nt][r] + bb[nt], im, im, im);
      *reinterpret_cast<float4*>(out + idx * 4) = o;
    }
  }
}

// ---------------- fallback: R2 fused kernel (relaxed launch bounds) ----------------
__global__ __launch_bounds__(256, 2) void fused_kernel(
    const float* __restrict__ x, const float* __restrict__ noise,
    const u32* __restrict__ ws,
    const float* __restrict__ b1, const float* __restrict__ b2,
    const float* __restrict__ b3, const float* __restrict__ b4,
    const float* __restrict__ omega, const float* __restrict__ Kp,
    const float* __restrict__ alphap, float* __restrict__ out) {
  const int tid = threadIdx.x;
  const int l = tid & 63;
  const int g = l >> 4, i = l & 15;
  const int m0 = blockIdx.x * 64 + (tid >> 6) * 16;

  f32x4 acc1T[4] = {};
  {
    const float* xr = x + (size_t)(m0 + i) * 512 + 4 * g;
#pragma unroll
    for (int kt = 0; kt < 16; ++kt) {
      const float4 a0 = *reinterpret_cast<const float4*>(xr + kt * 32);
      const float4 a1 = *reinterpret_cast<const float4*>(xr + kt * 32 + 16);
      union { u32 u[4]; bf16x8 v; } xf;
      xf.u[0] = pack2(a0.x, a0.y); xf.u[1] = pack2(a0.z, a0.w);
      xf.u[2] = pack2(a1.x, a1.y); xf.u[3] = pack2(a1.z, a1.w);
#pragma unroll
      for (int nt = 0; nt < 4; ++nt)
        acc1T[nt] = mfma16(ld_frag(ws + W1_OFF + (u32)(kt * 4 + nt) * 256u + (u32)l * 4u),
                           xf.v, acc1T[nt]);
    }
  }
  bf16x8 hfrag[2];
#pragma unroll
  for (int kt2 = 0; kt2 < 2; ++kt2) {
    union { u32 u[4]; bf16x8 v; } t;
#pragma unroll
    for (int q = 0; q < 2; ++q) {
      int nt = 2 * kt2 + q;
      int nb = 16 * nt + 4 * g;
      float v0 = tanhf(acc1T[nt][0] + b1[nb + 0]);
      float v1 = tanhf(acc1T[nt][1] + b1[nb + 1]);
      float v2 = tanhf(acc1T[nt][2] + b1[nb + 2]);
      float v3 = tanhf(acc1T[nt][3] + b1[nb + 3]);
      t.u[2 * q + 0] = pack2(v0, v1);
      t.u[2 * q + 1] = pack2(v2, v3);
    }
    hfrag[kt2] = t.v;
  }
  f32x4 acc2T[4] = {};
#pragma unroll
  for (int kt2 = 0; kt2 < 2; ++kt2)
#pragma unroll
    for (int ot = 0; ot < 4; ++ot)
      acc2T[ot] = mfma16(ld_frag(ws + W2_OFF + (u32)(kt2 * 4 + ot) * 256u + (u32)l * 4u),
                         hfrag[kt2], acc2T[ot]);
  float ph[4][4], om[4][4];
  const float Kc = Kp[0];
#pragma unroll
  for (int ot = 0; ot < 4; ++ot) {
    int ob = 16 * ot + 4 * g;
#pragma unroll
    for (int r = 0; r < 4; ++r) {
      ph[ot][r] = acc2T[ot][r] + b2[ob + r];
      om[ot][r] = omega[ob + r];
    }
  }
#pragma unroll
  for (int s = 0; s < 10; ++s) {
    float rs = 0.f;
    float cs[4][4];
#pragma unroll
    for (int ot = 0; ot < 4; ++ot)
#pragma unroll
      for (int r = 0; r < 4; ++r) {
        rs += __sinf(ph[ot][r]);
        cs[ot][r] = __cosf(ph[ot][r]);
      }
    rs += __shfl_xor(rs, 16);
    rs += __shfl_xor(rs, 32);
    float sc = 0.01f * Kc * rs * 0.015625f;
#pragma unroll
    for (int ot = 0; ot < 4; ++ot)
#pragma unroll
      for (int r = 0; r < 4; ++r)
        ph[ot][r] += 0.01f * om[ot][r] + sc * cs[ot][r];
  }
  bf16x8 pfrag[2];
#pragma unroll
  for (int kt2 = 0; kt2 < 2; ++kt2) {
    union { u32 u[4]; bf16x8 v; } t;
#pragma unroll
    for (int q = 0; q < 2; ++q) {
      int nt = 2 * kt2 + q;
      t.u[2 * q + 0] = pack2(ph[nt][0], ph[nt][1]);
      t.u[2 * q + 1] = pack2(ph[nt][2], ph[nt][3]);
    }
    pfrag[kt2] = t.v;
  }
  bf16x8 afr[16];
#pragma unroll
  for (int c = 0; c < 4; ++c) {
    f32x4 a3[8] = {};
#pragma unroll
    for (int kt = 0; kt < 2; ++kt)
#pragma unroll
      for (int nt = 0; nt < 8; ++nt)
        a3[nt] = mfma16(ld_frag(ws + W3_OFF + (u32)(kt * 32 + c * 8 + nt) * 256u + (u32)l * 4u),
                        pfrag[kt], a3[nt]);
#pragma unroll
    for (int q = 0; q < 4; ++q) {
      union { u32 u[4]; bf16x8 v; } t;
#pragma unroll
      for (int p = 0; p < 2; ++p) {
        int nt = 2 * q + p;
        int nb = 16 * (8 * c + nt) + 4 * g;
        float v0 = a3[nt][0] + b3[nb + 0]; v0 = v0 > 0.f ? v0 : 0.f;
        float v1 = a3[nt][1] + b3[nb + 1]; v1 = v1 > 0.f ? v1 : 0.f;
        float v2 = a3[nt][2] + b3[nb + 2]; v2 = v2 > 0.f ? v2 : 0.f;
        float v3 = a3[nt][3] + b3[nb + 3]; v3 = v3 > 0.f ? v3 : 0.f;
        t.u[2 * p + 0] = pack2(v0, v1);
        t.u[2 * p + 1] = pack2(v2, v3);
      }
      afr[4 * c + q] = t.v;
    }
  }
  const float alpha = alphap[0];
  for (int c4 = 0; c4 < 8; ++c4) {
    float nz[16];
#pragma unroll
    for (int nt = 0; nt < 4; ++nt)
#pragma unroll
      for (int r = 0; r < 4; ++r)
        nz[nt * 4 + r] = noise[(size_t)(m0 + 4 * g + r) * 512 + c4 * 64 + nt * 16 + i];
    f32x4 acc[4] = {};
#pragma unroll
    for (int kt = 0; kt < 16; ++kt)
#pragma unroll
      for (int nt = 0; nt < 4; ++nt)
        acc[nt] = mfma16(afr[kt],
                         ld_frag(ws + W4_OFF + (u32)(kt * 32 + c4 * 4 + nt) * 256u + (u32)l * 4u),
                         acc[nt]);
#pragma unroll
    for (int nt = 0; nt < 4; ++nt) {
      int col = c4 * 64 + nt * 16 + i;
      float bb = b4[col];
      float fmv = __sinf(alpha * (float)col);
#pragma unroll
      for (int r = 0; r < 4; ++r) {
        size_t idx = (size_t)(m0 + 4 * g + r) * 512 + col;
        float im = nz[nt * 4 + r] * fmv;
        float4 o = make_float4(acc[nt][r] + bb, im, im, im);
        *reinterpret_cast<float4*>(out + idx * 4) = o;
      }
    }
  }
}

extern "C" void kernel_launch(void* const* d_in, const int* in_sizes, int n_in,
                              void* d_out, int out_size, void* d_ws, size_t ws_size,
                              hipStream_t stream) {
  if (ws_size < WS_WEIGHTS_BYTES) return;
  const float* x      = (const float*)d_in[0];
  const float* noise  = (const float*)d_in[1];
  const float* W1     = (const float*)d_in[2];
  const float* b1     = (const float*)d_in[3];
  const float* W2     = (const float*)d_in[4];
  const float* b2     = (const float*)d_in[5];
  const float* W3     = (const float*)d_in[6];
  const float* b3     = (const float*)d_in[7];
  const float* W4     = (const float*)d_in[8];
  const float* b4     = (const float*)d_in[9];
  const float* omega  = (const float*)d_in[10];
  const float* Kp     = (const float*)d_in[11];
  const float* alphap = (const float*)d_in[12];
  u32* ws = (u32*)d_ws;
  prep_kernel<<<162, 256, 0, stream>>>(W1, W2, W3, W4, ws);
  if (ws_size >= WS_NEED_BYTES) {
    front_kernel<<<512, 256, 0, stream>>>(x, ws, ws, b1, b2, b3, omega, Kp);
    gemm4_kernel<<<2048, 512, 0, stream>>>(noise, ws, b4, alphap, (float*)d_out);
  } else {
    fused_kernel<<<512, 256, 0, stream>>>(x, noise, ws, b1, b2, b3, b4,
                                          omega, Kp, alphap, (float*)d_out);
  }
}